// Round 4
// baseline (137.902 us; speedup 1.0000x reference)
//
#include <hip/hip_runtime.h>
#include <hip/hip_bf16.h>

#define N_  16
#define L0_ 2048
#define L1_ 1024
#define D_  128
#define H_  384

// workspace layout (4-byte element offsets)
#define PM1_0 0        // float [32][16][128]
#define PM2_0 65536
#define PAM_0 131072   // int
#define PM1_1 196608   // float [16][16][128]
#define PM2_1 229376
#define PAM_1 262144   // int
#define BASE_ 294912   // float [2][16][128]
#define WBF_  299008   // bf16 [2][128][128] (32768 shorts = 16384 words)
#define HCNT_ 315392   // int [768]
#define HLIST_ 316160  // int [768][128][2]

typedef float  floatx4  __attribute__((ext_vector_type(4)));
typedef __bf16 bf16x8   __attribute__((ext_vector_type(8)));
typedef unsigned short ushortx8 __attribute__((ext_vector_type(8)));

__device__ __forceinline__ unsigned short f2bf(float f) {
  union { float f; unsigned int u; } v; v.f = f;
  unsigned int u = v.u;
  return (unsigned short)((u + 0x7fffu + ((u >> 16) & 1u)) >> 16);  // RNE
}

// ---------------------------------------------------------------------------
// Kernel 1: partial (top1, top2, argmax) per (tensor, n, d) over 64-row chunks
// grid 768: x0 -> 512 blocks (16 n x 32 chunks), x1 -> 256 (16 n x 16 chunks)
// ---------------------------------------------------------------------------
__global__ __launch_bounds__(256) void stats_kernel(
    const float* __restrict__ x0, const float* __restrict__ x1,
    float* __restrict__ ws) {
  __shared__ float sm1[8][128], sm2[8][128];
  __shared__ int   sam[8][128];
  int bid = blockIdx.x, tid = threadIdx.x;
  const float* x; int n, chunk, L; float *pm1, *pm2; int* pam;
  if (bid < 512) {
    x = x0; n = bid >> 5; chunk = bid & 31; L = L0_;
    pm1 = ws + PM1_0; pm2 = ws + PM2_0; pam = (int*)ws + PAM_0;
  } else {
    int b = bid - 512;
    x = x1; n = b >> 4; chunk = b & 15; L = L1_;
    pm1 = ws + PM1_1; pm2 = ws + PM2_1; pam = (int*)ws + PAM_1;
  }
  int q = tid & 31, sub = tid >> 5;
  int lbase = chunk * 64 + sub * 8;
  const float* xp = x + (size_t)(n * L + lbase) * D_ + q * 4;

  float m1[4], m2[4]; int am[4];
#pragma unroll
  for (int j = 0; j < 4; j++) { m1[j] = -3.4e38f; m2[j] = -3.4e38f; am[j] = 0; }
#pragma unroll
  for (int r = 0; r < 8; r++) {
    float4 v = *(const float4*)(xp + (size_t)r * D_);
    float vv[4] = { v.x, v.y, v.z, v.w };
    int l = lbase + r;
#pragma unroll
    for (int j = 0; j < 4; j++) {
      if (vv[j] > m1[j]) { m2[j] = m1[j]; m1[j] = vv[j]; am[j] = l; }
      else if (vv[j] > m2[j]) m2[j] = vv[j];
    }
  }
#pragma unroll
  for (int j = 0; j < 4; j++) {
    int d = q * 4 + j;
    sm1[sub][d] = m1[j]; sm2[sub][d] = m2[j]; sam[sub][d] = am[j];
  }
  __syncthreads();
  if (tid < 128) {
    int d = tid;
    float M1 = sm1[0][d], M2 = sm2[0][d]; int AM = sam[0][d];
#pragma unroll
    for (int s = 1; s < 8; s++) {
      float c1 = sm1[s][d];
      if (c1 > M1) { M2 = fmaxf(M1, sm2[s][d]); M1 = c1; AM = sam[s][d]; }
      else M2 = fmaxf(M2, c1);
    }
    int idx = (chunk * N_ + n) * D_ + d;
    pm1[idx] = M1; pm2[idx] = M2; pam[idx] = AM;
  }
}

// ---------------------------------------------------------------------------
// Kernel 2: per-(g,n) prep — merge partials, base GEMV, per-tile hit lists,
// bf16 W conversion. grid 32 (g*16+n), 256 threads.
// ---------------------------------------------------------------------------
__global__ __launch_bounds__(256) void prep_kernel(
    const float* __restrict__ W0, const float* __restrict__ b0,
    const float* __restrict__ W1, const float* __restrict__ b1,
    float* __restrict__ ws) {
  __shared__ float t1a[128], t1b[128], sdl[128], bpart[128];
  __shared__ int   sam2[128], scnt[32];
  int bid = blockIdx.x, tid = threadIdx.x;
  int g = bid >> 4, n = bid & 15;
  const float* W = g ? W1 : W0;
  const float* bias = g ? b1 : b0;

  if (tid < 32) scnt[tid] = 0;

  if (tid < 128) {        // merge x0 partials (32 chunks)
    int d = tid;
    const float* pm1 = ws + PM1_0; const float* pm2 = ws + PM2_0;
    const int* pam = (int*)ws + PAM_0;
    float M1 = pm1[n * D_ + d], M2 = pm2[n * D_ + d]; int AM = pam[n * D_ + d];
    for (int c = 1; c < 32; c++) {
      int id2 = (c * N_ + n) * D_ + d;
      float c1 = pm1[id2];
      if (c1 > M1) { M2 = fmaxf(M1, pm2[id2]); M1 = c1; AM = pam[id2]; }
      else M2 = fmaxf(M2, c1);
    }
    t1a[d] = M1;
    if (g == 0) { sdl[d] = M2 - M1; sam2[d] = AM; }
  } else {                // merge x1 partials (16 chunks)
    int d = tid - 128;
    const float* pm1 = ws + PM1_1; const float* pm2 = ws + PM2_1;
    const int* pam = (int*)ws + PAM_1;
    float M1 = pm1[n * D_ + d], M2 = pm2[n * D_ + d]; int AM = pam[n * D_ + d];
    for (int c = 1; c < 16; c++) {
      int id2 = (c * N_ + n) * D_ + d;
      float c1 = pm1[id2];
      if (c1 > M1) { M2 = fmaxf(M1, pm2[id2]); M1 = c1; AM = pam[id2]; }
      else M2 = fmaxf(M2, c1);
    }
    t1b[d] = M1;
    if (g == 1) { sdl[d] = M2 - M1; sam2[d] = AM; }
  }
  __syncthreads();

  // base[g][n][o] = bias[o] + t1a.W[o,128:256] + t1b.W[o,256:384]
  int o = tid & 127, half = tid >> 7;
  {
    const float* wr = W + (size_t)o * H_ + 128 + half * 128;
    const float* tv = half ? t1b : t1a;
    float bsum = 0.f;
#pragma unroll 4
    for (int d = 0; d < 128; d += 4) {
      float4 wv = *(const float4*)(wr + d);
      bsum += tv[d] * wv.x + tv[d + 1] * wv.y + tv[d + 2] * wv.z + tv[d + 3] * wv.w;
    }
    if (half) { bpart[o] = bsum; }
    __syncthreads();
    if (!half) ws[BASE_ + (g * N_ + n) * D_ + o] = bias[o] + bsum + bpart[o];
  }

  // scatter LOO corrections into per-64-row-tile lists
  if (tid < 128) {
    int d = tid; int am = sam2[d]; float dl = sdl[d];
    int t = am >> 6;
    int slot = atomicAdd(&scnt[t], 1);
    int tile = (g == 0) ? (n * 32 + t) : (512 + n * 16 + t);
    int* hl = (int*)ws + HLIST_ + tile * 256;
    hl[slot * 2]     = (am & 63) | (d << 8);
    hl[slot * 2 + 1] = __float_as_int(dl);
  }
  __syncthreads();
  int tcount = g ? 16 : 32;
  if (tid < tcount) {
    int tile = (g == 0) ? (n * 32 + tid) : (512 + n * 16 + tid);
    ((int*)ws)[HCNT_ + tile] = scnt[tid];
  }

  // bf16 conversion of W[:,0:128] (once per g)
  if (n == 0) {
    unsigned short* wbf = (unsigned short*)(ws + WBF_) + g * 16384;
#pragma unroll
    for (int it = 0; it < 64; it++) {
      int f = tid + 256 * it;
      int oo = f >> 7, k = f & 127;
      wbf[f] = f2bf(W[(size_t)oo * H_ + k]);
    }
  }
}

// ---------------------------------------------------------------------------
// Kernel 3: GEMM, swapped operands: A = W rows (m=o), B = x rows (n=l).
// D[m=o][n=l]: each lane holds 4 consecutive o for ONE x-row l -> float4
// stores. grid 768 (64-row tiles), 4 waves/block; wave: 16 x-rows x 128 o
// (8 MFMA tiles). No LDS, no barriers; x B-fragments hoisted ahead of K-loop.
// ---------------------------------------------------------------------------
__global__ __launch_bounds__(256) void gemm_kernel(
    const float* __restrict__ x0, const float* __restrict__ x1,
    const float* __restrict__ W0, const float* __restrict__ W1,
    float* __restrict__ out, const float* __restrict__ ws) {
  int bid = blockIdx.x, tid = threadIdx.x;
  int g, n, r0, L; const float *x, *W; float* y;
  if (bid < 512) { g = 0; n = bid >> 5; r0 = (bid & 31) << 6; L = L0_; x = x0; W = W0; y = out; }
  else { int b = bid - 512; g = 1; n = b >> 4; r0 = (b & 15) << 6; L = L1_; x = x1; W = W1;
         y = out + (size_t)N_ * L0_ * D_; }

  int w = tid >> 6, lane = tid & 63, lm = lane & 15, lq = lane >> 4;
  int lbase = r0 + w * 16;                 // this wave's 16 x-rows
  const float* xb = x + (size_t)(n * L + lbase) * D_;
  const unsigned short* wbf = (const unsigned short*)(ws + WBF_) + g * 16384;

  // hoist all 4 B fragments (x row lm, fp32 -> bf16), issued together for MLP
  bf16x8 bfr[4];
#pragma unroll
  for (int kk = 0; kk < 4; kk++) {
    const float* p = xb + (size_t)lm * D_ + kk * 32 + lq * 8;
    float4 u = *(const float4*)p;
    float4 v = *(const float4*)(p + 4);
    ushortx8 t = { f2bf(u.x), f2bf(u.y), f2bf(u.z), f2bf(u.w),
                   f2bf(v.x), f2bf(v.y), f2bf(v.z), f2bf(v.w) };
    bfr[kk] = __builtin_bit_cast(bf16x8, t);
  }

  floatx4 acc[8];
#pragma unroll
  for (int j = 0; j < 8; j++) acc[j] = (floatx4){0.f, 0.f, 0.f, 0.f};

#pragma unroll 1
  for (int kk = 0; kk < 4; kk++) {
    int ko = kk * 32 + lq * 8;
#pragma unroll
    for (int j = 0; j < 8; j++) {
      bf16x8 a = __builtin_bit_cast(bf16x8,
          *(const ushortx8*)&wbf[(j * 16 + lm) * 128 + ko]);
      acc[j] = __builtin_amdgcn_mfma_f32_16x16x32_bf16(a, bfr[kk], acc[j], 0, 0, 0);
    }
  }

  // sparse LOO corrections (fp32-exact): lane covers rows lm, o = j*16+lq*4+r
  int hc = ((const int*)ws)[HCNT_ + bid];
  const int* hl = (const int*)ws + HLIST_ + bid * 256;
  int off = 128 + (g << 7);
  for (int k = 0; k < hc; k++) {
    int e = hl[2 * k]; float dl = __int_as_float(hl[2 * k + 1]);
    int row = e & 63, d = e >> 8;
    if ((row >> 4) == w && (row & 15) == lm) {
#pragma unroll
      for (int j = 0; j < 8; j++)
#pragma unroll
        for (int r = 0; r < 4; r++)
          acc[j][r] += dl * W[(size_t)(j * 16 + lq * 4 + r) * H_ + off + d];
    }
  }

  // base + coalesced float4 stores: lane writes y[lbase+lm][j*16+lq*4 .. +3]
  const float* bp = ws + BASE_ + (g * N_ + n) * D_;
  float* yb = y + (size_t)(n * L + lbase + lm) * D_;
#pragma unroll
  for (int j = 0; j < 8; j++) {
    float4 bb = *(const float4*)&bp[j * 16 + lq * 4];
    float4 o4;
    o4.x = acc[j][0] + bb.x; o4.y = acc[j][1] + bb.y;
    o4.z = acc[j][2] + bb.z; o4.w = acc[j][3] + bb.w;
    *(float4*)&yb[j * 16 + lq * 4] = o4;
  }
}

extern "C" void kernel_launch(void* const* d_in, const int* in_sizes, int n_in,
                              void* d_out, int out_size, void* d_ws, size_t ws_size,
                              hipStream_t stream) {
  const float* x0 = (const float*)d_in[0];
  const float* x1 = (const float*)d_in[1];
  const float* W0 = (const float*)d_in[2];
  const float* b0 = (const float*)d_in[3];
  const float* W1 = (const float*)d_in[4];
  const float* b1 = (const float*)d_in[5];
  float* out = (float*)d_out;
  float* ws  = (float*)d_ws;

  hipLaunchKernelGGL(stats_kernel, dim3(768), dim3(256), 0, stream, x0, x1, ws);
  hipLaunchKernelGGL(prep_kernel,  dim3(32),  dim3(256), 0, stream, W0, b0, W1, b1, ws);
  hipLaunchKernelGGL(gemm_kernel,  dim3(768), dim3(256), 0, stream,
                     x0, x1, W0, W1, out, ws);
}